// Round 1
// baseline (1436.229 us; speedup 1.0000x reference)
//
#include <hip/hip_runtime.h>

// ---------------------------------------------------------------------------
// Fused point-cloud MHA + FFN for MI355X (gfx950).
// One workgroup = one (b,n) site. All intermediates live in LDS.
// GEMMs run on v_mfma_f32_16x16x32_bf16 with fp32 accumulate; residuals fp32.
// ---------------------------------------------------------------------------

#define B_   2
#define C_   384
#define N_   2048
#define K_   32
#define H_   6
#define DH_  64
#define C2_  768
#define NKE  (N_ * K_)          // 65536

// d_ws layout: bf16 weights then fp32 BN tables
#define WQ_OFF 0
#define WK_OFF (C_ * C_)                 // 147456
#define WV_OFF (2 * C_ * C_)             // 294912
#define W1_OFF (3 * C_ * C_)             // 442368
#define W2_OFF (3 * C_ * C_ + C2_ * C_)  // 737280
#define WTOT   (3 * C_ * C_ + 2 * C2_ * C_) // 1032192 bf16 elems
#define BN_INV_OFF (WTOT / 2)            // float index into (float*)ws
#define BN_SH_OFF  (WTOT / 2 + C2_)

typedef __attribute__((ext_vector_type(4))) float  f32x4;
typedef __attribute__((ext_vector_type(8))) __bf16 bf16x8;
typedef __attribute__((ext_vector_type(4))) short  s16x4;

__device__ __forceinline__ short f2bf(float f) {
  union { float f; unsigned u; } v; v.f = f;
  unsigned r = v.u + 0x7FFFu + ((v.u >> 16) & 1u);   // RNE
  return (short)(r >> 16);
}
__device__ __forceinline__ float bf2f(short s) {
  union { unsigned u; float f; } v; v.u = ((unsigned)(unsigned short)s) << 16;
  return v.f;
}

// ---- LDS geometry (bytes). Pads chosen so row strides are 16B-multiples and
// ---- fragment reads distribute uniformly over bank groups.
#define XLD  392   // [32 cols][384+8 cin] bf16 : XfT -> XqT -> aggT
#define VLD  40    // [384 c][32+8 k] bf16
#define PLD  40    // [6][32 q][32+8 k] bf16 softmax probs
#define H1LD 776   // [32 cols][768+8 cin] bf16 (overlays KT+QT)
#define XT_OFF  0
#define KT_OFF  25088
#define QT_OFF  50176
#define VC_OFF  75264
#define P_OFF   105984
#define SMEM_TOT 121344

// ---------------------------------------------------------------------------
// Weight fp32->bf16 conversion + BN fold (runs every launch; ws is re-poisoned)
// ---------------------------------------------------------------------------
__global__ void cvt_weights_kernel(const float* __restrict__ wq, const float* __restrict__ wk,
                                   const float* __restrict__ wv, const float* __restrict__ w1,
                                   const float* __restrict__ w2, const float* __restrict__ b1,
                                   const float* __restrict__ gamma, const float* __restrict__ beta,
                                   const float* __restrict__ rmean, const float* __restrict__ rvar,
                                   short* __restrict__ wsbf, float* __restrict__ wsf) {
  int i = blockIdx.x * 256 + threadIdx.x;
  if (i < WTOT) {
    float v;
    if      (i < WK_OFF) v = wq[i];
    else if (i < WV_OFF) v = wk[i - WK_OFF];
    else if (i < W1_OFF) v = wv[i - WV_OFF];
    else if (i < W2_OFF) v = w1[i - W1_OFF];
    else                 v = w2[i - W2_OFF];
    wsbf[i] = f2bf(v);
  } else if (i < WTOT + C2_) {
    int c = i - WTOT;
    float inv = gamma[c] * rsqrtf(rvar[c] + 1e-5f);
    wsf[BN_INV_OFF + c] = inv;
    // (x + b1)*inv + beta - rmean*inv  ==  x*inv + (b1*inv + beta - rmean*inv)
    wsf[BN_SH_OFF + c] = b1[c] * inv + beta[c] - rmean[c] * inv;
  }
}

// ---------------------------------------------------------------------------
// Inner GEMM: out[m0 + mt*16 + i][col] += sum_c W[row][c] * X[c][col]
// A (weights) streamed from global bf16 (row-major, stride wld).
// B from LDS xt = X transposed [col][cin], row stride xld (bf16 elems).
// NMT m-tiles per wave, 2 n-tiles (32 cols), NKK k-steps of 32.
// ---------------------------------------------------------------------------
template<int NMT, int NKK>
__device__ __forceinline__ void gemm_frag(const short* __restrict__ Wb, int wld, int m0,
                                          const short* xt, int xld, int lrow, int lhi,
                                          f32x4 (&acc)[NMT][2]) {
  const f32x4 zf = {0.f, 0.f, 0.f, 0.f};
  #pragma unroll
  for (int mt = 0; mt < NMT; ++mt) { acc[mt][0] = zf; acc[mt][1] = zf; }
  #pragma unroll
  for (int kk = 0; kk < NKK; ++kk) {
    const int ko = kk * 32 + lhi * 8;
    bf16x8 b0 = *(const bf16x8*)&xt[(lrow) * xld + ko];
    bf16x8 b1 = *(const bf16x8*)&xt[(16 + lrow) * xld + ko];
    #pragma unroll
    for (int mt = 0; mt < NMT; ++mt) {
      bf16x8 a = *(const bf16x8*)&Wb[(size_t)(m0 + mt * 16 + lrow) * wld + ko];
      acc[mt][0] = __builtin_amdgcn_mfma_f32_16x16x32_bf16(a, b0, acc[mt][0], 0, 0, 0);
      acc[mt][1] = __builtin_amdgcn_mfma_f32_16x16x32_bf16(a, b1, acc[mt][1], 0, 0, 0);
    }
  }
}

__launch_bounds__(512, 2)
__global__ void mha_fused_kernel(const float* __restrict__ queries,
                                 const float* __restrict__ feats,
                                 const float* __restrict__ bq,
                                 const float* __restrict__ bk,
                                 const float* __restrict__ bv,
                                 const float* __restrict__ b2,
                                 const short* __restrict__ wbf,
                                 const float* __restrict__ wsf,
                                 float* __restrict__ out) {
  __shared__ __align__(16) char smem[SMEM_TOT];
  short* XT = (short*)(smem + XT_OFF);   // X transposed / later aggT
  short* KT = (short*)(smem + KT_OFF);   // K transposed [k][c]
  short* QT = (short*)(smem + QT_OFF);   // Q transposed [q][c] (pre-scaled)
  short* VC = (short*)(smem + VC_OFF);   // V [c][k]
  short* Pb = (short*)(smem + P_OFF);    // probs [h][q][k]
  short* H1 = (short*)(smem + KT_OFF);   // h1 transposed [col][768] (overlays KT+QT)

  const int tid  = threadIdx.x;
  const int w    = tid >> 6;
  const int lane = tid & 63;
  const int lrow = lane & 15;
  const int lhi  = lane >> 4;

  const int site = blockIdx.x;
  const int b = site >> 11;          // site / N_
  const int n = site & (N_ - 1);
  const size_t base_bn = (size_t)b * C_ * NKE + (size_t)n * K_;  // + c*NKE + k

  // ---- P0: load feats -> XfT (transposed, bf16) -------------------------
  #pragma unroll
  for (int it = 0; it < 6; ++it) {
    int idx = it * 512 + tid;        // 0..3071
    int c  = idx >> 3;
    int k4 = (idx & 7) << 2;
    f32x4 v = *(const f32x4*)&feats[base_bn + (size_t)c * NKE + k4];
    #pragma unroll
    for (int j = 0; j < 4; ++j) XT[(k4 + j) * XLD + c] = f2bf(v[j]);
  }
  __syncthreads();

  // ---- P1: K and V projections (waves 0-3: K, waves 4-7: V) -------------
  {
    f32x4 acc[6][2];
    if (w < 4) {
      const int m0 = w * 96;
      gemm_frag<6, 12>(wbf + WK_OFF, C_, m0, XT, XLD, lrow, lhi, acc);
      #pragma unroll
      for (int mt = 0; mt < 6; ++mt) {
        const int cb = m0 + mt * 16 + lhi * 4;
        f32x4 bias = *(const f32x4*)&bk[cb];
        #pragma unroll
        for (int nt = 0; nt < 2; ++nt) {
          const int k = nt * 16 + lrow;
          s16x4 pk;
          #pragma unroll
          for (int r = 0; r < 4; ++r) pk[r] = f2bf(acc[mt][nt][r] + bias[r]);
          *(s16x4*)&KT[k * XLD + cb] = pk;       // transposed write, ds_write_b64
        }
      }
    } else {
      const int m0 = (w - 4) * 96;
      gemm_frag<6, 12>(wbf + WV_OFF, C_, m0, XT, XLD, lrow, lhi, acc);
      #pragma unroll
      for (int mt = 0; mt < 6; ++mt) {
        const int cb = m0 + mt * 16 + lhi * 4;
        f32x4 bias = *(const f32x4*)&bv[cb];
        #pragma unroll
        for (int nt = 0; nt < 2; ++nt) {
          const int k = nt * 16 + lrow;
          #pragma unroll
          for (int r = 0; r < 4; ++r) VC[(cb + r) * VLD + k] = f2bf(acc[mt][nt][r] + bias[r]);
        }
      }
    }
  }
  __syncthreads();

  // ---- P2: load queries -> XqT (overwrites XfT) -------------------------
  #pragma unroll
  for (int it = 0; it < 6; ++it) {
    int idx = it * 512 + tid;
    int c  = idx >> 3;
    int k4 = (idx & 7) << 2;
    f32x4 v = *(const f32x4*)&queries[base_bn + (size_t)c * NKE + k4];
    #pragma unroll
    for (int j = 0; j < 4; ++j) XT[(k4 + j) * XLD + c] = f2bf(v[j]);
  }
  __syncthreads();

  // ---- P3: Q projection, pre-scaled by DH^-0.5, stored transposed -------
  {
    f32x4 acc[3][2];
    const int m0 = w * 48;
    gemm_frag<3, 12>(wbf + WQ_OFF, C_, m0, XT, XLD, lrow, lhi, acc);
    #pragma unroll
    for (int mt = 0; mt < 3; ++mt) {
      const int cb = m0 + mt * 16 + lhi * 4;
      f32x4 bias = *(const f32x4*)&bq[cb];
      #pragma unroll
      for (int nt = 0; nt < 2; ++nt) {
        const int q = nt * 16 + lrow;
        s16x4 pk;
        #pragma unroll
        for (int r = 0; r < 4; ++r) pk[r] = f2bf((acc[mt][nt][r] + bias[r]) * 0.125f);
        *(s16x4*)&QT[q * XLD + cb] = pk;
      }
    }
  }
  __syncthreads();

  // ---- P4a: per-head logits + in-register wave softmax (wave w = head w) -
  if (w < H_) {
    const int hd0 = w * DH_;
    f32x4 lac[2][2] = {};
    #pragma unroll
    for (int kk = 0; kk < 2; ++kk) {
      const int ko = hd0 + kk * 32 + lhi * 8;
      bf16x8 aq0 = *(const bf16x8*)&QT[(lrow) * XLD + ko];
      bf16x8 aq1 = *(const bf16x8*)&QT[(16 + lrow) * XLD + ko];
      bf16x8 bk0 = *(const bf16x8*)&KT[(lrow) * XLD + ko];
      bf16x8 bk1 = *(const bf16x8*)&KT[(16 + lrow) * XLD + ko];
      lac[0][0] = __builtin_amdgcn_mfma_f32_16x16x32_bf16(aq0, bk0, lac[0][0], 0, 0, 0);
      lac[0][1] = __builtin_amdgcn_mfma_f32_16x16x32_bf16(aq0, bk1, lac[0][1], 0, 0, 0);
      lac[1][0] = __builtin_amdgcn_mfma_f32_16x16x32_bf16(aq1, bk0, lac[1][0], 0, 0, 0);
      lac[1][1] = __builtin_amdgcn_mfma_f32_16x16x32_bf16(aq1, bk1, lac[1][1], 0, 0, 0);
    }
    // softmax rows: lane holds L[q = mt*16 + lhi*4 + r][k = lrow and 16+lrow]
    #pragma unroll
    for (int mt = 0; mt < 2; ++mt) {
      #pragma unroll
      for (int r = 0; r < 4; ++r) {
        float v0 = lac[mt][0][r], v1 = lac[mt][1][r];
        float m = fmaxf(v0, v1);
        m = fmaxf(m, __shfl_xor(m, 1));
        m = fmaxf(m, __shfl_xor(m, 2));
        m = fmaxf(m, __shfl_xor(m, 4));
        m = fmaxf(m, __shfl_xor(m, 8));
        float e0 = __expf(v0 - m), e1 = __expf(v1 - m);
        float s = e0 + e1;
        s += __shfl_xor(s, 1);
        s += __shfl_xor(s, 2);
        s += __shfl_xor(s, 4);
        s += __shfl_xor(s, 8);
        float inv = 1.0f / s;
        const int q = mt * 16 + lhi * 4 + r;
        Pb[(w * 32 + q) * PLD + lrow]      = f2bf(e0 * inv);
        Pb[(w * 32 + q) * PLD + 16 + lrow] = f2bf(e1 * inv);
      }
    }
  }
  __syncthreads();

  // ---- P4b: agg^T = P @ V^T, + queries residual (fp32), stored bf16 -----
  if (w < H_) {
    const int hd0 = w * DH_;
    const f32x4 zf = {0.f, 0.f, 0.f, 0.f};
    bf16x8 pA[2];
    pA[0] = *(const bf16x8*)&Pb[(w * 32 + lrow) * PLD + lhi * 8];
    pA[1] = *(const bf16x8*)&Pb[(w * 32 + 16 + lrow) * PLD + lhi * 8];
    #pragma unroll
    for (int nt = 0; nt < 4; ++nt) {
      bf16x8 vB = *(const bf16x8*)&VC[(hd0 + nt * 16 + lrow) * VLD + lhi * 8];
      #pragma unroll
      for (int mt = 0; mt < 2; ++mt) {
        f32x4 acc = __builtin_amdgcn_mfma_f32_16x16x32_bf16(pA[mt], vB, zf, 0, 0, 0);
        const int c  = hd0 + nt * 16 + lrow;
        const int q0 = mt * 16 + lhi * 4;
        f32x4 res = *(const f32x4*)&queries[base_bn + (size_t)c * NKE + q0];
        #pragma unroll
        for (int r = 0; r < 4; ++r)
          XT[(q0 + r) * XLD + c] = f2bf(acc[r] + res[r]);   // aggT overwrites XqT
      }
    }
  }
  __syncthreads();

  // ---- P5: FFN1 h1 = relu(bn(W1@agg)), h1T overlays KT+QT ---------------
  {
    f32x4 acc[6][2];
    const int m0 = w * 96;
    gemm_frag<6, 12>(wbf + W1_OFF, C_, m0, XT, XLD, lrow, lhi, acc);
    #pragma unroll
    for (int mt = 0; mt < 6; ++mt) {
      const int ob = m0 + mt * 16 + lhi * 4;
      f32x4 inv = *(const f32x4*)&wsf[BN_INV_OFF + ob];
      f32x4 sh  = *(const f32x4*)&wsf[BN_SH_OFF + ob];
      #pragma unroll
      for (int nt = 0; nt < 2; ++nt) {
        const int col = nt * 16 + lrow;
        s16x4 pk;
        #pragma unroll
        for (int r = 0; r < 4; ++r) {
          float h = acc[mt][nt][r] * inv[r] + sh[r];
          pk[r] = f2bf(fmaxf(h, 0.f));
        }
        *(s16x4*)&H1[col * H1LD + ob] = pk;
      }
    }
  }
  __syncthreads();

  // ---- P6: FFN2 out = relu(W2@h1 + b2 + agg), store fp32 ----------------
  {
    f32x4 acc[3][2];
    const int m0 = w * 48;
    gemm_frag<3, 24>(wbf + W2_OFF, C2_, m0, H1, H1LD, lrow, lhi, acc);
    #pragma unroll
    for (int mt = 0; mt < 3; ++mt) {
      const int ob = m0 + mt * 16 + lhi * 4;
      f32x4 bias = *(const f32x4*)&b2[ob];
      #pragma unroll
      for (int nt = 0; nt < 2; ++nt) {
        const int q = nt * 16 + lrow;
        s16x4 ag = *(const s16x4*)&XT[q * XLD + ob];
        #pragma unroll
        for (int r = 0; r < 4; ++r) {
          float v = acc[mt][nt][r] + bias[r] + bf2f(ag[r]);
          out[base_bn + (size_t)(ob + r) * NKE + q] = fmaxf(v, 0.f);
        }
      }
    }
  }
}

extern "C" void kernel_launch(void* const* d_in, const int* in_sizes, int n_in,
                              void* d_out, int out_size, void* d_ws, size_t ws_size,
                              hipStream_t stream) {
  const float* queries = (const float*)d_in[0];
  const float* feats   = (const float*)d_in[1];
  const float* Wq = (const float*)d_in[2];
  const float* bq = (const float*)d_in[3];
  const float* Wk = (const float*)d_in[4];
  const float* bk = (const float*)d_in[5];
  const float* Wv = (const float*)d_in[6];
  const float* bv = (const float*)d_in[7];
  const float* W1 = (const float*)d_in[8];
  const float* b1 = (const float*)d_in[9];
  const float* gamma = (const float*)d_in[10];
  const float* beta  = (const float*)d_in[11];
  const float* rmean = (const float*)d_in[12];
  const float* rvar  = (const float*)d_in[13];
  const float* W2 = (const float*)d_in[14];
  const float* b2 = (const float*)d_in[15];
  float* out  = (float*)d_out;
  short* wsbf = (short*)d_ws;
  float* wsf  = (float*)d_ws;

  cvt_weights_kernel<<<(WTOT + C2_ + 255) / 256, 256, 0, stream>>>(
      Wq, Wk, Wv, W1, W2, b1, gamma, beta, rmean, rvar, wsbf, wsf);

  mha_fused_kernel<<<B_ * N_, 512, 0, stream>>>(
      queries, feats, bq, bk, bv, b2, wsbf, wsf, out);
}